// Round 2
// baseline (3378.880 us; speedup 1.0000x reference)
//
#include <hip/hip_runtime.h>
#include <stdint.h>

#define GAS __attribute__((address_space(1)))
#define LAS __attribute__((address_space(3)))

typedef unsigned short u16;
typedef short short8 __attribute__((ext_vector_type(8)));
typedef __bf16 bf16x8 __attribute__((ext_vector_type(8)));
typedef float floatx4 __attribute__((ext_vector_type(4)));

// ---------- bf16 helpers (RNE) ----------
__device__ __forceinline__ u16 f2bf(float f) {
  uint32_t u = __builtin_bit_cast(uint32_t, f);
  u += 0x7FFFu + ((u >> 16) & 1u);
  return (u16)(u >> 16);
}
__device__ __forceinline__ float bf2f(u16 h) {
  return __builtin_bit_cast(float, (uint32_t)h << 16);
}
// hi + lo == v to ~2^-17 relative
__device__ __forceinline__ void split_bf(float v, u16& hi, u16& lo) {
  hi = f2bf(v);
  float r = v - bf2f(hi);
  if (!(r == r)) r = 0.f;
  lo = f2bf(r);
}

// monotone float atomic max (pos: signed int max; neg: unsigned min). Safe under any interleaving.
__device__ __forceinline__ void atomicMaxF(float* addr, float val) {
  if (!(val > *(volatile const float*)addr)) return;
  if (val >= 0.f) atomicMax((int*)addr, __builtin_bit_cast(int, val));
  else            atomicMin((unsigned int*)addr, __builtin_bit_cast(unsigned int, val));
}

// async global->LDS, 16B/lane; lds base wave-uniform (HW adds lane*16)
__device__ __forceinline__ void async16(const void* g, const void* lds) {
  __builtin_amdgcn_global_load_lds((GAS const uint32_t*)g, (LAS uint32_t*)lds, 16, 0, 0);
}

__device__ __forceinline__ floatx4 mfma_bf16(short8 a, short8 b, floatx4 c) {
  return __builtin_amdgcn_mfma_f32_16x16x32_bf16(
      __builtin_bit_cast(bf16x8, a), __builtin_bit_cast(bf16x8, b), c, 0, 0, 0);
}

// ---------- small kernels ----------
__global__ void k_init(float* __restrict__ g, float* __restrict__ out, int ng, int no) {
  int i = blockIdx.x * 256 + threadIdx.x;
  if (i < ng) g[i] = -INFINITY;
  else if (i < ng + no) out[i - ng] = -INFINITY;
}

// h1 = feat@W1 + b1 for a point chunk; stores chunk-local hi/lo planes
__global__ void k_h1(const float* __restrict__ feat, const float* __restrict__ W1,
                     const float* __restrict__ b1,
                     u16* __restrict__ h1hi, u16* __restrict__ h1lo,
                     int pt_off, int npts_chunk) {
  int gid = blockIdx.x * 256 + threadIdx.x;
  int p = gid >> 7, c = gid & 127;
  if (p >= npts_chunk) return;
  int pg = pt_off + p;
  float v = b1[c];
#pragma unroll
  for (int j = 0; j < 11; ++j) v += feat[pg * 11 + j] * W1[j * 128 + c];
  u16 hi, lo; split_bf(v, hi, lo);
  h1hi[gid] = hi; h1lo[gid] = lo;
}

// W[K][N] f32 -> Bt[N][3K] bf16 rows [Whi ; Wlo ; Whi] (K-major per col)
__global__ void k_wprep(const float* __restrict__ W, u16* __restrict__ bt, int K, int N) {
  int gid = blockIdx.x * 256 + threadIdx.x;
  if (gid >= K * N) return;
  int c = gid / K, k = gid - c * K;
  float v = W[(size_t)k * N + c];
  u16 hi, lo; split_bf(v, hi, lo);
  size_t b = (size_t)c * (3 * K);
  bt[b + k] = hi; bt[b + K + k] = lo; bt[b + 2 * K + k] = hi;
}

// W23 = W2 @ W3[256:512,:]  (fp32); b23 = b3 + b2 @ W3[256:512,:]
__global__ void k_w23(const float* __restrict__ W2, const float* __restrict__ W3,
                      const float* __restrict__ b2, const float* __restrict__ b3,
                      float* __restrict__ W23, float* __restrict__ b23) {
  int gid = blockIdx.x * 256 + threadIdx.x;
  if (gid < 128 * 512) {
    int j = gid >> 9, c = gid & 511;
    float s = 0.f;
#pragma unroll 4
    for (int t = 0; t < 256; ++t) s += W2[j * 256 + t] * W3[(size_t)(256 + t) * 512 + c];
    W23[gid] = s;
  } else if (gid < 128 * 512 + 512) {
    int c = gid - 128 * 512;
    float s = b3[c];
    for (int t = 0; t < 256; ++t) s += b2[t] * W3[(size_t)(256 + t) * 512 + c];
    b23[c] = s;
  }
}

// B3t[N=512][K'=1152]: K=384 rows = [W3_top(256) ; W23(128)], regions [hi;lo;hi]
__global__ void k_prep3(const float* __restrict__ W3, const float* __restrict__ W23,
                        u16* __restrict__ bt) {
  int gid = blockIdx.x * 256 + threadIdx.x;
  if (gid >= 512 * 384) return;
  int c = gid / 384, k = gid - c * 384;
  float v = (k < 256) ? W3[(size_t)k * 512 + c] : W23[(size_t)(k - 256) * 512 + c];
  u16 hi, lo; split_bf(v, hi, lo);
  size_t b = (size_t)c * 1152;
  bt[b + k] = hi; bt[b + 384 + k] = lo; bt[b + 768 + k] = hi;
}

__global__ void k_gsplit(const float* __restrict__ g, u16* __restrict__ ghi,
                         u16* __restrict__ glo, int n) {
  int i = blockIdx.x * 256 + threadIdx.x;
  if (i >= n) return;
  u16 hi, lo; split_bf(g[i], hi, lo);
  ghi[i] = hi; glo[i] = lo;
}

// ---------- the workhorse GEMM ----------
// C[128x128]/block, BK=64, 4 waves (2x2), 4x4 frags of 16x16x32 bf16.
// MODE 0: A = h1 chunk {hi,hi,lo} stride 128, KP=384;  epi: +b2, atomicMax -> g      (NT=2)
// MODE 1: A = [g[idx](256) | h1(128)] {hi,hi,lo}, KP=1152; epi: +b23, relu, -> z1    (NT=4)
// MODE 2: A = z1 chunk {hi,hi,lo} stride 512, KP=1536; epi: +b4, atomicMax -> out    (NT=3)
template <int MODE, int KP, int NT>
__global__ __launch_bounds__(256) void k_gemm(
    const u16* __restrict__ a0, const u16* __restrict__ a1,
    const u16* __restrict__ a2, const u16* __restrict__ a3,
    const u16* __restrict__ bt, const float* __restrict__ bias,
    const int* __restrict__ idx, int mt0,
    float* __restrict__ gmax, u16* __restrict__ whi, u16* __restrict__ wlo) {
  __shared__ __align__(16) u16 As[128 * 64];
  __shared__ __align__(16) u16 Bs[128 * 64];
  const int tid = threadIdx.x;
  const int w = tid >> 6, lane = tid & 63;
  const int mtl = blockIdx.x / NT, ct = blockIdx.x % NT;
  const int wr = w & 1, wc = w >> 1;
  const int l15 = lane & 15, l4 = lane >> 4;
  const int sub = lane >> 3;
  const int kc8 = (lane & 7) * 8;

  int arl[4], argl[4], bcol[4], gq[4];
#pragma unroll
  for (int q = 0; q < 4; ++q) {
    int rr = (q * 4 + w) * 8 + sub;
    arl[q] = mtl * 128 + rr;               // chunk-local row
    argl[q] = (mt0 + mtl) * 128 + rr;      // global row
    bcol[q] = ct * 128 + rr;
    if constexpr (MODE == 1) gq[q] = idx[argl[q]];
  }

  floatx4 zero = {0.f, 0.f, 0.f, 0.f};
  floatx4 acc[4][4];
#pragma unroll
  for (int mi = 0; mi < 4; ++mi)
#pragma unroll
    for (int ni = 0; ni < 4; ++ni) acc[mi][ni] = zero;

  for (int kt = 0; kt < KP / 64; ++kt) {
    const int kbase = kt * 64 + kc8;
#pragma unroll
    for (int q = 0; q < 4; ++q) {
      const u16* src;
      if constexpr (MODE == 0) {
        int r = kbase >> 7, k = kbase & 127;          // regions of 128: hi,hi,lo
        src = ((r == 2) ? a1 : a0) + (size_t)arl[q] * 128 + k;
      } else if constexpr (MODE == 1) {
        int r = kbase / 384, inner = kbase - (kbase / 384) * 384;  // regions of 384
        bool lo = (r == 2);
        if (inner < 256) src = (lo ? a2 : a0) + (size_t)gq[q] * 256 + inner;
        else             src = (lo ? a3 : a1) + (size_t)arl[q] * 128 + (inner - 256);
      } else {
        int r = kbase >> 9, inner = kbase & 511;      // regions of 512
        src = ((r == 2) ? a1 : a0) + (size_t)arl[q] * 512 + inner;
      }
      async16(src, &As[(q * 4 + w) * 512]);
    }
#pragma unroll
    for (int q = 0; q < 4; ++q)
      async16(bt + (size_t)bcol[q] * KP + kbase, &Bs[(q * 4 + w) * 512]);
    __syncthreads();  // drains vmcnt+lgkmcnt -> staged data visible
#pragma unroll
    for (int kk = 0; kk < 2; ++kk) {
      short8 af[4], bfr[4];
#pragma unroll
      for (int mi = 0; mi < 4; ++mi)
        af[mi] = *(const short8*)&As[(wr * 64 + mi * 16 + l15) * 64 + kk * 32 + l4 * 8];
#pragma unroll
      for (int ni = 0; ni < 4; ++ni)
        bfr[ni] = *(const short8*)&Bs[(wc * 64 + ni * 16 + l15) * 64 + kk * 32 + l4 * 8];
#pragma unroll
      for (int mi = 0; mi < 4; ++mi)
#pragma unroll
        for (int ni = 0; ni < 4; ++ni)
          acc[mi][ni] = mfma_bf16(af[mi], bfr[ni], acc[mi][ni]);
    }
    __syncthreads();
  }

  // ---- epilogue (C/D: col=lane&15, row=(lane>>4)*4+reg) ----
#pragma unroll
  for (int ni = 0; ni < 4; ++ni) {
    const int col = ct * 128 + wc * 64 + ni * 16 + l15;
    const float bv = bias[col];
#pragma unroll
    for (int mi = 0; mi < 4; ++mi) {
      const int rl0 = mtl * 128 + wr * 64 + mi * 16 + l4 * 4;
#pragma unroll
      for (int r = 0; r < 4; ++r) {
        float v = acc[mi][ni][r] + bv;
        const int rl = rl0 + r;
        const int rg = mt0 * 128 + rl;
        if constexpr (MODE == 0) {
          atomicMaxF(&gmax[(size_t)idx[rg] * 256 + col], v);
        } else if constexpr (MODE == 1) {
          v = fmaxf(v, 0.f);
          u16 hi, lo; split_bf(v, hi, lo);
          whi[(size_t)rl * 512 + col] = hi;
          wlo[(size_t)rl * 512 + col] = lo;
        } else {
          atomicMaxF(&gmax[(size_t)idx[rg] * 384 + col], v);
        }
      }
    }
  }
}

// ---------- launch ----------
extern "C" void kernel_launch(void* const* d_in, const int* in_sizes, int n_in,
                              void* d_out, int out_size, void* d_ws, size_t ws_size,
                              hipStream_t stream) {
  const float* feat = (const float*)d_in[0];
  const int* sidx   = (const int*)d_in[1];
  const float* W1 = (const float*)d_in[3];
  const float* b1 = (const float*)d_in[4];
  const float* W2 = (const float*)d_in[5];
  const float* b2 = (const float*)d_in[6];
  const float* W3 = (const float*)d_in[7];
  const float* b3 = (const float*)d_in[8];
  const float* W4 = (const float*)d_in[9];
  const float* b4 = (const float*)d_in[10];
  float* out = (float*)d_out;
  (void)n_in;

  const int S  = out_size / 384;  // 4096
  const int NP = in_sizes[1];     // 400000 (multiple of 128)
  const int MT = NP / 128;        // 3125

  char* ws = (char*)d_ws;
  size_t off = 0;
  auto carve = [&](size_t bytes) -> void* {
    void* p = ws + off;
    off += (bytes + 255) & ~(size_t)255;
    return p;
  };
  // persistent (~11 MB)
  float* g   = (float*)carve((size_t)S * 256 * 4);
  u16* ghi   = (u16*)carve((size_t)S * 256 * 2);
  u16* glo   = (u16*)carve((size_t)S * 256 * 2);
  u16* B2t   = (u16*)carve((size_t)256 * 384 * 2);
  u16* B3t   = (u16*)carve((size_t)512 * 1152 * 2);
  u16* B4t   = (u16*)carve((size_t)384 * 1536 * 2);
  float* W23 = (float*)carve((size_t)128 * 512 * 4);
  float* b23 = (float*)carve((size_t)512 * 4);

  // chunk-local buffers sized from remaining ws: per 128-row block:
  // h1 hi/lo = 128*128*2*2 = 64 KiB ; z1 hi/lo = 128*512*2*2 = 256 KiB
  const size_t per_block = (size_t)128 * (128 * 2 * 2 + 512 * 2 * 2) + 4 * 256;
  size_t remain = (ws_size > off + 4096) ? (ws_size - off - 4096) : 0;
  int cb = (int)(remain / per_block);
  if (cb < 1) cb = 1;
  if (cb > MT) cb = MT;
  u16* h1hi = (u16*)carve((size_t)cb * 128 * 128 * 2);
  u16* h1lo = (u16*)carve((size_t)cb * 128 * 128 * 2);
  u16* z1hi = (u16*)carve((size_t)cb * 128 * 512 * 2);
  u16* z1lo = (u16*)carve((size_t)cb * 128 * 512 * 2);

  // init g, out to -inf (ws/out are poisoned each call)
  k_init<<<(S * (256 + 384) + 255) / 256, 256, 0, stream>>>(g, out, S * 256, S * 384);
  // weight preps
  k_wprep<<<(128 * 256 + 255) / 256, 256, 0, stream>>>(W2, B2t, 128, 256);
  k_w23<<<(128 * 512 + 512 + 255) / 256, 256, 0, stream>>>(W2, W3, b2, b3, W23, b23);
  k_prep3<<<(512 * 384 + 255) / 256, 256, 0, stream>>>(W3, W23, B3t);
  k_wprep<<<(512 * 384 + 255) / 256, 256, 0, stream>>>(W4, B4t, 512, 384);

  // phase A: g = segmax(h1@W2+b2)
  for (int done = 0; done < MT; done += cb) {
    int nb = (MT - done < cb) ? (MT - done) : cb;
    int pts = nb * 128;
    k_h1<<<(pts * 128) / 256, 256, 0, stream>>>(feat, W1, b1, h1hi, h1lo, done * 128, pts);
    k_gemm<0, 384, 2><<<nb * 2, 256, 0, stream>>>(
        h1hi, h1lo, nullptr, nullptr, B2t, b2, sidx, done, g, nullptr, nullptr);
  }
  k_gsplit<<<(S * 256 + 255) / 256, 256, 0, stream>>>(g, ghi, glo, S * 256);

  // phase C: z1 = relu([g[idx]|h1]@[W3_top;W23]+b23) ; out = segmax(z1@W4+b4)
  for (int done = 0; done < MT; done += cb) {
    int nb = (MT - done < cb) ? (MT - done) : cb;
    int pts = nb * 128;
    k_h1<<<(pts * 128) / 256, 256, 0, stream>>>(feat, W1, b1, h1hi, h1lo, done * 128, pts);
    k_gemm<1, 1152, 4><<<nb * 4, 256, 0, stream>>>(
        ghi, h1hi, glo, h1lo, B3t, b23, sidx, done, nullptr, z1hi, z1lo);
    k_gemm<2, 1536, 3><<<nb * 3, 256, 0, stream>>>(
        z1hi, z1lo, nullptr, nullptr, B4t, b4, sidx, done, out, nullptr, nullptr);
  }
}

// Round 4
// 3057.599 us; speedup vs baseline: 1.1051x; 1.1051x over previous
//
#include <hip/hip_runtime.h>
#include <stdint.h>

#define GAS __attribute__((address_space(1)))
#define LAS __attribute__((address_space(3)))

typedef unsigned short u16;
typedef short short8 __attribute__((ext_vector_type(8)));
typedef __bf16 bf16x8 __attribute__((ext_vector_type(8)));
typedef float floatx4 __attribute__((ext_vector_type(4)));

// ---------- bf16 helpers (RNE) ----------
__device__ __forceinline__ u16 f2bf(float f) {
  uint32_t u = __builtin_bit_cast(uint32_t, f);
  u += 0x7FFFu + ((u >> 16) & 1u);
  return (u16)(u >> 16);
}
__device__ __forceinline__ float bf2f(u16 h) {
  return __builtin_bit_cast(float, (uint32_t)h << 16);
}
__device__ __forceinline__ void split_bf(float v, u16& hi, u16& lo) {
  hi = f2bf(v);
  float r = v - bf2f(hi);
  if (!(r == r)) r = 0.f;
  lo = f2bf(r);
}

// monotone float atomic max (pos: signed max; neg: unsigned min); read-check filters losers
__device__ __forceinline__ void atomicMaxF(float* addr, float val) {
  if (!(val > *(volatile const float*)addr)) return;
  if (val >= 0.f) atomicMax((int*)addr, __builtin_bit_cast(int, val));
  else            atomicMin((unsigned int*)addr, __builtin_bit_cast(unsigned int, val));
}

__device__ __forceinline__ void async16(const void* g, const void* lds) {
  __builtin_amdgcn_global_load_lds((GAS const uint32_t*)g, (LAS uint32_t*)lds, 16, 0, 0);
}

__device__ __forceinline__ floatx4 mfma_bf16(short8 a, short8 b, floatx4 c) {
  return __builtin_amdgcn_mfma_f32_16x16x32_bf16(
      __builtin_bit_cast(bf16x8, a), __builtin_bit_cast(bf16x8, b), c, 0, 0, 0);
}

// ---------- init: g/out = -inf, hist = 0 ----------
__global__ void k_init(float* __restrict__ g, float* __restrict__ out,
                       int* __restrict__ hist, int ng, int no, int nh) {
  int i = blockIdx.x * 256 + threadIdx.x;
  if (i < ng) g[i] = -INFINITY;
  else if (i < ng + no) out[i - ng] = -INFINITY;
  else if (i < ng + no + nh) hist[i - ng - no] = 0;
}

// ---------- counting sort of points by segment ----------
__global__ void k_hist(const int* __restrict__ idx, int* __restrict__ hist, int n) {
  int p = blockIdx.x * 256 + threadIdx.x;
  if (p < n) atomicAdd(&hist[idx[p]], 1);
}

// 1 block, 1024 threads: exclusive scan of hist[4096] -> offs & cur
__global__ __launch_bounds__(1024) void k_scan(const int* __restrict__ hist,
                                               int* __restrict__ offs, int* __restrict__ cur) {
  __shared__ int buf[2][1024];
  int t = threadIdx.x;
  int local[4];
  int s = 0;
#pragma unroll
  for (int j = 0; j < 4; ++j) { local[j] = hist[t * 4 + j]; s += local[j]; }
  buf[0][t] = s;
  __syncthreads();
  int pb = 0;
  for (int d = 1; d < 1024; d <<= 1) {
    int v = buf[pb][t] + (t >= d ? buf[pb][t - d] : 0);
    buf[pb ^ 1][t] = v;
    pb ^= 1;
    __syncthreads();
  }
  int run = (t == 0) ? 0 : buf[pb][t - 1];
#pragma unroll
  for (int j = 0; j < 4; ++j) { offs[t * 4 + j] = run; cur[t * 4 + j] = run; run += local[j]; }
}

__global__ void k_scatter(const int* __restrict__ idx, int* __restrict__ cur,
                          int* __restrict__ perm, int* __restrict__ segp, int n) {
  int p = blockIdx.x * 256 + threadIdx.x;
  if (p >= n) return;
  int s = idx[p];
  int r = atomicAdd(&cur[s], 1);
  perm[r] = p;
  segp[r] = s;
}

// ---------- h1 = feat[perm]@W1 + b1 for a sorted-row chunk ----------
__global__ void k_h1(const float* __restrict__ feat, const int* __restrict__ perm,
                     const float* __restrict__ W1, const float* __restrict__ b1,
                     u16* __restrict__ h1hi, u16* __restrict__ h1lo,
                     int pt_off, int npts_chunk) {
  int gid = blockIdx.x * 256 + threadIdx.x;
  int p = gid >> 7, c = gid & 127;
  if (p >= npts_chunk) return;
  int o = perm[pt_off + p];
  float v = b1[c];
#pragma unroll
  for (int j = 0; j < 11; ++j) v += feat[o * 11 + j] * W1[j * 128 + c];
  u16 hi, lo; split_bf(v, hi, lo);
  h1hi[gid] = hi; h1lo[gid] = lo;
}

// ---------- weight preps ----------
// W[K][N] f32 -> Bt[N][3K] bf16 rows [Whi ; Wlo ; Whi]
__global__ void k_wprep(const float* __restrict__ W, u16* __restrict__ bt, int K, int N) {
  int gid = blockIdx.x * 256 + threadIdx.x;
  if (gid >= K * N) return;
  int c = gid / K, k = gid - c * K;
  float v = W[(size_t)k * N + c];
  u16 hi, lo; split_bf(v, hi, lo);
  size_t b = (size_t)c * (3 * K);
  bt[b + k] = hi; bt[b + K + k] = lo; bt[b + 2 * K + k] = hi;
}

// W23 = W2 @ W3[256:512,:]; b23 = b3 + b2 @ W3[256:512,:]
__global__ void k_w23(const float* __restrict__ W2, const float* __restrict__ W3,
                      const float* __restrict__ b2, const float* __restrict__ b3,
                      float* __restrict__ W23, float* __restrict__ b23) {
  int gid = blockIdx.x * 256 + threadIdx.x;
  if (gid < 128 * 512) {
    int j = gid >> 9, c = gid & 511;
    float s = 0.f;
#pragma unroll 4
    for (int t = 0; t < 256; ++t) s += W2[j * 256 + t] * W3[(size_t)(256 + t) * 512 + c];
    W23[gid] = s;
  } else if (gid < 128 * 512 + 512) {
    int c = gid - 128 * 512;
    float s = b3[c];
    for (int t = 0; t < 256; ++t) s += b2[t] * W3[(size_t)(256 + t) * 512 + c];
    b23[c] = s;
  }
}

// B3t[512][1152]: K=384 rows = [W3_top(256) ; W23(128)], regions [hi;lo;hi]
__global__ void k_prep3(const float* __restrict__ W3, const float* __restrict__ W23,
                        u16* __restrict__ bt) {
  int gid = blockIdx.x * 256 + threadIdx.x;
  if (gid >= 512 * 384) return;
  int c = gid / 384, k = gid - c * 384;
  float v = (k < 256) ? W3[(size_t)k * 512 + c] : W23[(size_t)(k - 256) * 512 + c];
  u16 hi, lo; split_bf(v, hi, lo);
  size_t b = (size_t)c * 1152;
  bt[b + k] = hi; bt[b + 384 + k] = lo; bt[b + 768 + k] = hi;
}

__global__ void k_gsplit(const float* __restrict__ g, u16* __restrict__ ghi,
                         u16* __restrict__ glo, int n) {
  int i = blockIdx.x * 256 + threadIdx.x;
  if (i >= n) return;
  u16 hi, lo; split_bf(g[i], hi, lo);
  ghi[i] = hi; glo[i] = lo;
}

// ---------- the workhorse GEMM (rows are segment-sorted) ----------
// C[128x128]/block, BK=64, 4 waves (2x2), 4x4 frags of 16x16x32 bf16.
// MODE 0: A = h1 {hi,hi,lo} stride 128, KP=384;  epi: +b2, run-reduced segmax -> g   (NT=2)
// MODE 1: A = [g[seg](256) | h1(128)] {hi,hi,lo}, KP=1152; epi: +b23, relu -> z1     (NT=4)
// MODE 2: A = z1 {hi,hi,lo} stride 512, KP=1536; epi: +b4, run-reduced segmax -> out (NT=3)
template <int MODE, int KP, int NT, int CW>
__global__ __launch_bounds__(256) void k_gemm(
    const u16* __restrict__ a0, const u16* __restrict__ a1,
    const u16* __restrict__ a2, const u16* __restrict__ a3,
    const u16* __restrict__ bt, const float* __restrict__ bias,
    const int* __restrict__ segp, int mt0,
    float* __restrict__ gmax, u16* __restrict__ whi, u16* __restrict__ wlo) {
  __shared__ __align__(16) union {
    struct { u16 A[128 * 64]; u16 B[128 * 64]; } st;
    float ct[128 * 66];
  } sm;
  const int tid = threadIdx.x;
  const int w = tid >> 6, lane = tid & 63;
  const int mtl = blockIdx.x / NT, ct = blockIdx.x % NT;
  const int wr = w & 1, wc = w >> 1;
  const int l15 = lane & 15, l4 = lane >> 4;
  const int sub = lane >> 3;
  const int kc8 = (lane & 7) * 8;

  int arl[4], bcol[4], gq[4];
#pragma unroll
  for (int q = 0; q < 4; ++q) {
    int rr = (q * 4 + w) * 8 + sub;
    arl[q] = mtl * 128 + rr;
    bcol[q] = ct * 128 + rr;
    if constexpr (MODE == 1) gq[q] = segp[(mt0 + mtl) * 128 + rr];
  }

  floatx4 zero = {0.f, 0.f, 0.f, 0.f};
  floatx4 acc[4][4];
#pragma unroll
  for (int mi = 0; mi < 4; ++mi)
#pragma unroll
    for (int ni = 0; ni < 4; ++ni) acc[mi][ni] = zero;

  for (int kt = 0; kt < KP / 64; ++kt) {
    const int kbase = kt * 64 + kc8;
#pragma unroll
    for (int q = 0; q < 4; ++q) {
      const u16* src;
      if constexpr (MODE == 0) {
        int r = kbase >> 7, k = kbase & 127;
        src = ((r == 2) ? a1 : a0) + (size_t)arl[q] * 128 + k;
      } else if constexpr (MODE == 1) {
        int r = kbase / 384, inner = kbase - r * 384;
        bool lo = (r == 2);
        if (inner < 256) src = (lo ? a2 : a0) + (size_t)gq[q] * 256 + inner;
        else             src = (lo ? a3 : a1) + (size_t)arl[q] * 128 + (inner - 256);
      } else {
        int r = kbase >> 9, inner = kbase & 511;
        src = ((r == 2) ? a1 : a0) + (size_t)arl[q] * 512 + inner;
      }
      async16(src, &sm.st.A[(q * 4 + w) * 512]);
    }
#pragma unroll
    for (int q = 0; q < 4; ++q)
      async16(bt + (size_t)bcol[q] * KP + kbase, &sm.st.B[(q * 4 + w) * 512]);
    __syncthreads();
#pragma unroll
    for (int kk = 0; kk < 2; ++kk) {
      short8 af[4], bfr[4];
#pragma unroll
      for (int mi = 0; mi < 4; ++mi)
        af[mi] = *(const short8*)&sm.st.A[(wr * 64 + mi * 16 + l15) * 64 + kk * 32 + l4 * 8];
#pragma unroll
      for (int ni = 0; ni < 4; ++ni)
        bfr[ni] = *(const short8*)&sm.st.B[(wc * 64 + ni * 16 + l15) * 64 + kk * 32 + l4 * 8];
#pragma unroll
      for (int mi = 0; mi < 4; ++mi)
#pragma unroll
        for (int ni = 0; ni < 4; ++ni)
          acc[mi][ni] = mfma_bf16(af[mi], bfr[ni], acc[mi][ni]);
    }
    __syncthreads();
  }

  if constexpr (MODE == 1) {
    // store z1 hi/lo (chunk-local, sorted order). C/D: col=lane&15, row=(lane>>4)*4+reg
#pragma unroll
    for (int ni = 0; ni < 4; ++ni) {
      const int col = ct * 128 + wc * 64 + ni * 16 + l15;
      const float bv = bias[col];
#pragma unroll
      for (int mi = 0; mi < 4; ++mi) {
        const int rl0 = mtl * 128 + wr * 64 + mi * 16 + l4 * 4;
#pragma unroll
        for (int r = 0; r < 4; ++r) {
          float v = fmaxf(acc[mi][ni][r] + bv, 0.f);
          u16 hi, lo; split_bf(v, hi, lo);
          whi[(size_t)(rl0 + r) * 512 + col] = hi;
          wlo[(size_t)(rl0 + r) * 512 + col] = lo;
        }
      }
    }
  } else {
    // run-reduced segment max: two 64-col halves through LDS [128][66] f32
#pragma unroll
    for (int h = 0; h < 2; ++h) {
      __syncthreads();
      if (wc == h) {
#pragma unroll
        for (int ni = 0; ni < 4; ++ni) {
          const int cl = ni * 16 + l15;  // 0..63 within half
          const float bv = bias[ct * 128 + h * 64 + cl];
#pragma unroll
          for (int mi = 0; mi < 4; ++mi) {
            const int row0 = wr * 64 + mi * 16 + l4 * 4;
#pragma unroll
            for (int r = 0; r < 4; ++r)
              sm.ct[(row0 + r) * 66 + cl] = acc[mi][ni][r] + bv;
          }
        }
      }
      __syncthreads();
      if (tid < 128) {
        const int col = tid & 63, rh = tid >> 6;
        const int cg = ct * 128 + h * 64 + col;
        const int base = (mt0 + mtl) * 128 + rh * 64;
        float run = sm.ct[(rh * 64) * 66 + col];
        int curs = segp[base];
        for (int r = 1; r < 64; ++r) {
          int s = segp[base + r];
          float v = sm.ct[(rh * 64 + r) * 66 + col];
          if (s != curs) {
            atomicMaxF(&gmax[(size_t)curs * CW + cg], run);
            run = v; curs = s;
          } else {
            run = fmaxf(run, v);
          }
        }
        atomicMaxF(&gmax[(size_t)curs * CW + cg], run);
      }
    }
  }
}

// ---------- launch ----------
extern "C" void kernel_launch(void* const* d_in, const int* in_sizes, int n_in,
                              void* d_out, int out_size, void* d_ws, size_t ws_size,
                              hipStream_t stream) {
  const float* feat = (const float*)d_in[0];
  const int* sidx   = (const int*)d_in[1];
  const float* W1 = (const float*)d_in[3];
  const float* b1 = (const float*)d_in[4];
  const float* W2 = (const float*)d_in[5];
  const float* b2 = (const float*)d_in[6];
  const float* W3 = (const float*)d_in[7];
  const float* b3 = (const float*)d_in[8];
  const float* W4 = (const float*)d_in[9];
  const float* b4 = (const float*)d_in[10];
  float* out = (float*)d_out;
  (void)n_in;

  const int S  = out_size / 384;  // 4096
  const int NP = in_sizes[1];     // 400000 (multiple of 128)
  const int MT = NP / 128;        // 3125

  char* ws = (char*)d_ws;
  size_t off = 0;
  auto carve = [&](size_t bytes) -> void* {
    void* p = ws + off;
    off += (bytes + 255) & ~(size_t)255;
    return p;
  };
  // persistent (~15 MB)
  float* g   = (float*)carve((size_t)S * 256 * 4);
  u16* ghi   = (u16*)carve((size_t)S * 256 * 2);
  u16* glo   = (u16*)carve((size_t)S * 256 * 2);
  u16* B2t   = (u16*)carve((size_t)256 * 384 * 2);
  u16* B3t   = (u16*)carve((size_t)512 * 1152 * 2);
  u16* B4t   = (u16*)carve((size_t)384 * 1536 * 2);
  float* W23 = (float*)carve((size_t)128 * 512 * 4);
  float* b23 = (float*)carve((size_t)512 * 4);
  int* hist  = (int*)carve((size_t)S * 4);
  int* offs  = (int*)carve((size_t)S * 4);
  int* curp  = (int*)carve((size_t)S * 4);
  int* perm  = (int*)carve((size_t)NP * 4);
  int* segp  = (int*)carve((size_t)NP * 4);

  // chunk-local: per 128-row block: h1 64 KiB + z1 256 KiB
  const size_t per_block = (size_t)128 * (128 * 2 * 2 + 512 * 2 * 2) + 4 * 256;
  size_t remain = (ws_size > off + 4096) ? (ws_size - off - 4096) : 0;
  int cb = (int)(remain / per_block);
  if (cb < 1) cb = 1;
  if (cb > MT) cb = MT;
  u16* h1hi = (u16*)carve((size_t)cb * 128 * 128 * 2);
  u16* h1lo = (u16*)carve((size_t)cb * 128 * 128 * 2);
  u16* z1hi = (u16*)carve((size_t)cb * 128 * 512 * 2);
  u16* z1lo = (u16*)carve((size_t)cb * 128 * 512 * 2);

  // init + sort
  k_init<<<(S * (256 + 384 + 1) + 255) / 256, 256, 0, stream>>>(g, out, hist,
                                                                S * 256, S * 384, S);
  k_hist<<<(NP + 255) / 256, 256, 0, stream>>>(sidx, hist, NP);
  k_scan<<<1, 1024, 0, stream>>>(hist, offs, curp);
  k_scatter<<<(NP + 255) / 256, 256, 0, stream>>>(sidx, curp, perm, segp, NP);

  // weight preps
  k_wprep<<<(128 * 256 + 255) / 256, 256, 0, stream>>>(W2, B2t, 128, 256);
  k_w23<<<(128 * 512 + 512 + 255) / 256, 256, 0, stream>>>(W2, W3, b2, b3, W23, b23);
  k_prep3<<<(512 * 384 + 255) / 256, 256, 0, stream>>>(W3, W23, B3t);
  k_wprep<<<(512 * 384 + 255) / 256, 256, 0, stream>>>(W4, B4t, 512, 384);

  // phase A: g = segmax(h1@W2+b2)
  for (int done = 0; done < MT; done += cb) {
    int nb = (MT - done < cb) ? (MT - done) : cb;
    int pts = nb * 128;
    k_h1<<<(pts * 128) / 256, 256, 0, stream>>>(feat, perm, W1, b1, h1hi, h1lo,
                                                done * 128, pts);
    k_gemm<0, 384, 2, 256><<<nb * 2, 256, 0, stream>>>(
        h1hi, h1lo, nullptr, nullptr, B2t, b2, segp, done, g, nullptr, nullptr);
  }
  k_gsplit<<<(S * 256 + 255) / 256, 256, 0, stream>>>(g, ghi, glo, S * 256);

  // phase C: z1 = relu([g[seg]|h1]@[W3_top;W23]+b23) ; out = segmax(z1@W4+b4)
  for (int done = 0; done < MT; done += cb) {
    int nb = (MT - done < cb) ? (MT - done) : cb;
    int pts = nb * 128;
    k_h1<<<(pts * 128) / 256, 256, 0, stream>>>(feat, perm, W1, b1, h1hi, h1lo,
                                                done * 128, pts);
    k_gemm<1, 1152, 4, 0><<<nb * 4, 256, 0, stream>>>(
        ghi, h1hi, glo, h1lo, B3t, b23, segp, done, nullptr, z1hi, z1lo);
    k_gemm<2, 1536, 3, 384><<<nb * 3, 256, 0, stream>>>(
        z1hi, z1lo, nullptr, nullptr, B4t, b4, segp, done, out, nullptr, nullptr);
  }
}

// Round 8
// 2636.698 us; speedup vs baseline: 1.2815x; 1.1596x over previous
//
#include <hip/hip_runtime.h>
#include <stdint.h>

#define GAS __attribute__((address_space(1)))
#define LAS __attribute__((address_space(3)))

typedef unsigned short u16;
typedef short short8 __attribute__((ext_vector_type(8)));
typedef __bf16 bf16x8 __attribute__((ext_vector_type(8)));
typedef float floatx4 __attribute__((ext_vector_type(4)));

// ---------- bf16 helpers (RNE) ----------
__device__ __forceinline__ u16 f2bf(float f) {
  uint32_t u = __builtin_bit_cast(uint32_t, f);
  u += 0x7FFFu + ((u >> 16) & 1u);
  return (u16)(u >> 16);
}
__device__ __forceinline__ float bf2f(u16 h) {
  return __builtin_bit_cast(float, (uint32_t)h << 16);
}
__device__ __forceinline__ void split_bf(float v, u16& hi, u16& lo) {
  hi = f2bf(v);
  float r = v - bf2f(hi);
  if (!(r == r)) r = 0.f;
  lo = f2bf(r);
}

// monotone float atomic max (pos: signed max; neg: unsigned min); read-check filters losers
__device__ __forceinline__ void atomicMaxF(float* addr, float val) {
  if (!(val > *(volatile const float*)addr)) return;
  if (val >= 0.f) atomicMax((int*)addr, __builtin_bit_cast(int, val));
  else            atomicMin((unsigned int*)addr, __builtin_bit_cast(unsigned int, val));
}

__device__ __forceinline__ void async16(const void* g, const void* lds) {
  __builtin_amdgcn_global_load_lds((GAS const uint32_t*)g, (LAS uint32_t*)lds, 16, 0, 0);
}

__device__ __forceinline__ floatx4 mfma_bf16(short8 a, short8 b, floatx4 c) {
  return __builtin_amdgcn_mfma_f32_16x16x32_bf16(
      __builtin_bit_cast(bf16x8, a), __builtin_bit_cast(bf16x8, b), c, 0, 0, 0);
}

// ---------- init: g/out = -inf, hist = 0 ----------
__global__ void k_init(float* __restrict__ g, float* __restrict__ out,
                       int* __restrict__ hist, int ng, int no, int nh) {
  int i = blockIdx.x * 256 + threadIdx.x;
  if (i < ng) g[i] = -INFINITY;
  else if (i < ng + no) out[i - ng] = -INFINITY;
  else if (i < ng + no + nh) hist[i - ng - no] = 0;
}

// ---------- counting sort of points by segment ----------
__global__ void k_hist(const int* __restrict__ idx, int* __restrict__ hist, int n) {
  int p = blockIdx.x * 256 + threadIdx.x;
  if (p < n) atomicAdd(&hist[idx[p]], 1);
}

// 1 block, 1024 threads: exclusive scan of hist[4096] -> offs & cur
__global__ __launch_bounds__(1024) void k_scan(const int* __restrict__ hist,
                                               int* __restrict__ offs, int* __restrict__ cur) {
  __shared__ int buf[2][1024];
  int t = threadIdx.x;
  int local[4];
  int s = 0;
#pragma unroll
  for (int j = 0; j < 4; ++j) { local[j] = hist[t * 4 + j]; s += local[j]; }
  buf[0][t] = s;
  __syncthreads();
  int pb = 0;
  for (int d = 1; d < 1024; d <<= 1) {
    int v = buf[pb][t] + (t >= d ? buf[pb][t - d] : 0);
    buf[pb ^ 1][t] = v;
    pb ^= 1;
    __syncthreads();
  }
  int run = (t == 0) ? 0 : buf[pb][t - 1];
#pragma unroll
  for (int j = 0; j < 4; ++j) { offs[t * 4 + j] = run; cur[t * 4 + j] = run; run += local[j]; }
}

__global__ void k_scatter(const int* __restrict__ idx, int* __restrict__ cur,
                          int* __restrict__ perm, int* __restrict__ segp, int n) {
  int p = blockIdx.x * 256 + threadIdx.x;
  if (p >= n) return;
  int s = idx[p];
  int r = atomicAdd(&cur[s], 1);
  perm[r] = p;
  segp[r] = s;
}

// ---------- h1 = feat[perm]@W1 + b1 for a sorted-row chunk ----------
__global__ void k_h1(const float* __restrict__ feat, const int* __restrict__ perm,
                     const float* __restrict__ W1, const float* __restrict__ b1,
                     u16* __restrict__ h1hi, u16* __restrict__ h1lo,
                     int pt_off, int npts_chunk) {
  int gid = blockIdx.x * 256 + threadIdx.x;
  int p = gid >> 7, c = gid & 127;
  if (p >= npts_chunk) return;
  int o = perm[pt_off + p];
  float v = b1[c];
#pragma unroll
  for (int j = 0; j < 11; ++j) v += feat[o * 11 + j] * W1[j * 128 + c];
  u16 hi, lo; split_bf(v, hi, lo);
  h1hi[gid] = hi; h1lo[gid] = lo;
}

// ---------- weight preps ----------
// W[K][N] f32 -> Bt[N][3K] bf16 rows [Whi ; Wlo ; Whi]
__global__ void k_wprep(const float* __restrict__ W, u16* __restrict__ bt, int K, int N) {
  int gid = blockIdx.x * 256 + threadIdx.x;
  if (gid >= K * N) return;
  int c = gid / K, k = gid - c * K;
  float v = W[(size_t)k * N + c];
  u16 hi, lo; split_bf(v, hi, lo);
  size_t b = (size_t)c * (3 * K);
  bt[b + k] = hi; bt[b + K + k] = lo; bt[b + 2 * K + k] = hi;
}

// W23 = W2 @ W3[256:512,:]; b23 = b3 + b2 @ W3[256:512,:]
__global__ void k_w23(const float* __restrict__ W2, const float* __restrict__ W3,
                      const float* __restrict__ b2, const float* __restrict__ b3,
                      float* __restrict__ W23, float* __restrict__ b23) {
  int gid = blockIdx.x * 256 + threadIdx.x;
  if (gid < 128 * 512) {
    int j = gid >> 9, c = gid & 511;
    float s = 0.f;
#pragma unroll 4
    for (int t = 0; t < 256; ++t) s += W2[j * 256 + t] * W3[(size_t)(256 + t) * 512 + c];
    W23[gid] = s;
  } else if (gid < 128 * 512 + 512) {
    int c = gid - 128 * 512;
    float s = b3[c];
    for (int t = 0; t < 256; ++t) s += b2[t] * W3[(size_t)(256 + t) * 512 + c];
    b23[c] = s;
  }
}

// B3t[512][1152]: K=384 rows = [W3_top(256) ; W23(128)], regions [hi;lo;hi]
__global__ void k_prep3(const float* __restrict__ W3, const float* __restrict__ W23,
                        u16* __restrict__ bt) {
  int gid = blockIdx.x * 256 + threadIdx.x;
  if (gid >= 512 * 384) return;
  int c = gid / 384, k = gid - c * 384;
  float v = (k < 256) ? W3[(size_t)k * 512 + c] : W23[(size_t)(k - 256) * 512 + c];
  u16 hi, lo; split_bf(v, hi, lo);
  size_t b = (size_t)c * 1152;
  bt[b + k] = hi; bt[b + 384 + k] = lo; bt[b + 768 + k] = hi;
}

__global__ void k_gsplit(const float* __restrict__ g, u16* __restrict__ ghi,
                         u16* __restrict__ glo, int n) {
  int i = blockIdx.x * 256 + threadIdx.x;
  if (i >= n) return;
  u16 hi, lo; split_bf(g[i], hi, lo);
  ghi[i] = hi; glo[i] = lo;
}

// ---------- the workhorse GEMM (rows segment-sorted, 2-phase dbuf pipeline) ----------
// C[128x128]/block, BK=64, 4 waves (2x2), 4x4 frags of 16x16x32 bf16.
// Double-buffered LDS: STAGE(t+1) issued before compute(t); ONE barrier per K-step
// (its vmcnt(0)+lgkmcnt(0) drain makes buf[t+1] visible AND proves buf[t] fully read).
// XCD swizzle: contiguous work ranges per XCD -> NT column-tile siblings share L2.
// MODE 0: A = h1 {hi,hi,lo} stride 128, KP=384;  epi: +b2, run-reduced segmax -> g   (NT=2)
// MODE 1: A = [g[seg](256) | h1(128)] {hi,hi,lo}, KP=1152; epi: +b23, relu -> z1     (NT=4)
// MODE 2: A = z1 {hi,hi,lo} stride 512, KP=1536; epi: +b4, run-reduced segmax -> out (NT=3)
template <int MODE, int KP, int NT, int CW>
__global__ __launch_bounds__(256) void k_gemm(
    const u16* __restrict__ a0, const u16* __restrict__ a1,
    const u16* __restrict__ a2, const u16* __restrict__ a3,
    const u16* __restrict__ bt, const float* __restrict__ bias,
    const int* __restrict__ segp, int mt0, int nb,
    float* __restrict__ gmax, u16* __restrict__ whi, u16* __restrict__ wlo) {
  __shared__ __align__(16) union {
    struct { u16 A[2][128 * 64]; u16 B[2][128 * 64]; } st;
    float ct[128 * 66];
  } sm;
  const int tid = threadIdx.x;
  const int w = tid >> 6, lane = tid & 63;

  // XCD-sibling swizzle: work = mtl*NT+ct; contiguous work per XCD (assumes bid%8 = xcd)
  const int work_total = nb * NT;
  const int spx = (work_total + 7) >> 3;
  const int wk = (blockIdx.x & 7) * spx + (blockIdx.x >> 3);
  if (wk >= work_total) return;
  const int mtl = wk / NT, ct = wk - mtl * NT;

  const int wr = w & 1, wc = w >> 1;
  const int l15 = lane & 15, l4 = lane >> 4;
  const int sub = lane >> 3;
  const int kc8 = (lane & 7) * 8;

  int arl[4], bcol[4], gq[4];
#pragma unroll
  for (int q = 0; q < 4; ++q) {
    int rr = (q * 4 + w) * 8 + sub;
    arl[q] = mtl * 128 + rr;
    bcol[q] = ct * 128 + rr;
    if constexpr (MODE == 1) gq[q] = segp[(mt0 + mtl) * 128 + rr];
  }

  auto stage = [&](int kt, int buf) {
    const int kbase = kt * 64 + kc8;
#pragma unroll
    for (int q = 0; q < 4; ++q) {
      const u16* src;
      if constexpr (MODE == 0) {
        int r = kbase >> 7, k = kbase & 127;
        src = ((r == 2) ? a1 : a0) + (size_t)arl[q] * 128 + k;
      } else if constexpr (MODE == 1) {
        int r = kbase / 384, inner = kbase - r * 384;
        bool lo = (r == 2);
        if (inner < 256) src = (lo ? a2 : a0) + (size_t)gq[q] * 256 + inner;
        else             src = (lo ? a3 : a1) + (size_t)arl[q] * 128 + (inner - 256);
      } else {
        int r = kbase >> 9, inner = kbase & 511;
        src = ((r == 2) ? a1 : a0) + (size_t)arl[q] * 512 + inner;
      }
      async16(src, &sm.st.A[buf][(q * 4 + w) * 512]);
    }
#pragma unroll
    for (int q = 0; q < 4; ++q)
      async16(bt + (size_t)bcol[q] * KP + kbase, &sm.st.B[buf][(q * 4 + w) * 512]);
  };

  floatx4 zero = {0.f, 0.f, 0.f, 0.f};
  floatx4 acc[4][4];
#pragma unroll
  for (int mi = 0; mi < 4; ++mi)
#pragma unroll
    for (int ni = 0; ni < 4; ++ni) acc[mi][ni] = zero;

  constexpr int NKT = KP / 64;
  stage(0, 0);
  __syncthreads();
  int cur = 0;
  for (int kt = 0; kt < NKT; ++kt) {
    if (kt + 1 < NKT) stage(kt + 1, cur ^ 1);  // prefetch overlaps compute below
#pragma unroll
    for (int kk = 0; kk < 2; ++kk) {
      short8 af[4], bfr[4];
#pragma unroll
      for (int mi = 0; mi < 4; ++mi)
        af[mi] = *(const short8*)&sm.st.A[cur][(wr * 64 + mi * 16 + l15) * 64 + kk * 32 + l4 * 8];
#pragma unroll
      for (int ni = 0; ni < 4; ++ni)
        bfr[ni] = *(const short8*)&sm.st.B[cur][(wc * 64 + ni * 16 + l15) * 64 + kk * 32 + l4 * 8];
#pragma unroll
      for (int mi = 0; mi < 4; ++mi)
#pragma unroll
        for (int ni = 0; ni < 4; ++ni)
          acc[mi][ni] = mfma_bf16(af[mi], bfr[ni], acc[mi][ni]);
    }
    __syncthreads();  // drains vmcnt (next buf staged) + proves cur fully consumed
    cur ^= 1;
  }

  if constexpr (MODE == 1) {
    // store z1 hi/lo (chunk-local, sorted order). C/D: col=lane&15, row=(lane>>4)*4+reg
#pragma unroll
    for (int ni = 0; ni < 4; ++ni) {
      const int col = ct * 128 + wc * 64 + ni * 16 + l15;
      const float bv = bias[col];
#pragma unroll
      for (int mi = 0; mi < 4; ++mi) {
        const int rl0 = mtl * 128 + wr * 64 + mi * 16 + l4 * 4;
#pragma unroll
        for (int r = 0; r < 4; ++r) {
          float v = fmaxf(acc[mi][ni][r] + bv, 0.f);
          u16 hi, lo; split_bf(v, hi, lo);
          whi[(size_t)(rl0 + r) * 512 + col] = hi;
          wlo[(size_t)(rl0 + r) * 512 + col] = lo;
        }
      }
    }
  } else {
    // run-reduced segment max: two 64-col halves through LDS [128][66] f32
#pragma unroll
    for (int h = 0; h < 2; ++h) {
      __syncthreads();
      if (wc == h) {
#pragma unroll
        for (int ni = 0; ni < 4; ++ni) {
          const int cl = ni * 16 + l15;  // 0..63 within half
          const float bv = bias[ct * 128 + h * 64 + cl];
#pragma unroll
          for (int mi = 0; mi < 4; ++mi) {
            const int row0 = wr * 64 + mi * 16 + l4 * 4;
#pragma unroll
            for (int r = 0; r < 4; ++r)
              sm.ct[(row0 + r) * 66 + cl] = acc[mi][ni][r] + bv;
          }
        }
      }
      __syncthreads();
      if (tid < 128) {
        const int col = tid & 63, rh = tid >> 6;
        const int cg = ct * 128 + h * 64 + col;
        const int base = (mt0 + mtl) * 128 + rh * 64;
        float run = sm.ct[(rh * 64) * 66 + col];
        int curs = segp[base];
        for (int r = 1; r < 64; ++r) {
          int s = segp[base + r];
          float v = sm.ct[(rh * 64 + r) * 66 + col];
          if (s != curs) {
            atomicMaxF(&gmax[(size_t)curs * CW + cg], run);
            run = v; curs = s;
          } else {
            run = fmaxf(run, v);
          }
        }
        atomicMaxF(&gmax[(size_t)curs * CW + cg], run);
      }
    }
  }
}

// ---------- launch ----------
static inline int swgrid(int work) { return 8 * ((work + 7) / 8); }

extern "C" void kernel_launch(void* const* d_in, const int* in_sizes, int n_in,
                              void* d_out, int out_size, void* d_ws, size_t ws_size,
                              hipStream_t stream) {
  const float* feat = (const float*)d_in[0];
  const int* sidx   = (const int*)d_in[1];
  const float* W1 = (const float*)d_in[3];
  const float* b1 = (const float*)d_in[4];
  const float* W2 = (const float*)d_in[5];
  const float* b2 = (const float*)d_in[6];
  const float* W3 = (const float*)d_in[7];
  const float* b3 = (const float*)d_in[8];
  const float* W4 = (const float*)d_in[9];
  const float* b4 = (const float*)d_in[10];
  float* out = (float*)d_out;
  (void)n_in;

  const int S  = out_size / 384;  // 4096
  const int NP = in_sizes[1];     // 400000 (multiple of 128)
  const int MT = NP / 128;        // 3125

  char* ws = (char*)d_ws;
  size_t off = 0;
  auto carve = [&](size_t bytes) -> void* {
    void* p = ws + off;
    off += (bytes + 255) & ~(size_t)255;
    return p;
  };
  // persistent (~15 MB)
  float* g   = (float*)carve((size_t)S * 256 * 4);
  u16* ghi   = (u16*)carve((size_t)S * 256 * 2);
  u16* glo   = (u16*)carve((size_t)S * 256 * 2);
  u16* B2t   = (u16*)carve((size_t)256 * 384 * 2);
  u16* B3t   = (u16*)carve((size_t)512 * 1152 * 2);
  u16* B4t   = (u16*)carve((size_t)384 * 1536 * 2);
  float* W23 = (float*)carve((size_t)128 * 512 * 4);
  float* b23 = (float*)carve((size_t)512 * 4);
  int* hist  = (int*)carve((size_t)S * 4);
  int* offs  = (int*)carve((size_t)S * 4);
  int* curp  = (int*)carve((size_t)S * 4);
  int* perm  = (int*)carve((size_t)NP * 4);
  int* segp  = (int*)carve((size_t)NP * 4);

  // chunk-local: per 128-row block: h1 64 KiB + z1 256 KiB
  const size_t per_block = (size_t)128 * (128 * 2 * 2 + 512 * 2 * 2) + 4 * 256;
  size_t remain = (ws_size > off + 4096) ? (ws_size - off - 4096) : 0;
  int cb = (int)(remain / per_block);
  if (cb < 1) cb = 1;
  if (cb > MT) cb = MT;
  u16* h1hi = (u16*)carve((size_t)cb * 128 * 128 * 2);
  u16* h1lo = (u16*)carve((size_t)cb * 128 * 128 * 2);
  u16* z1hi = (u16*)carve((size_t)cb * 128 * 512 * 2);
  u16* z1lo = (u16*)carve((size_t)cb * 128 * 512 * 2);

  // init + sort
  k_init<<<(S * (256 + 384 + 1) + 255) / 256, 256, 0, stream>>>(g, out, hist,
                                                                S * 256, S * 384, S);
  k_hist<<<(NP + 255) / 256, 256, 0, stream>>>(sidx, hist, NP);
  k_scan<<<1, 1024, 0, stream>>>(hist, offs, curp);
  k_scatter<<<(NP + 255) / 256, 256, 0, stream>>>(sidx, curp, perm, segp, NP);

  // weight preps
  k_wprep<<<(128 * 256 + 255) / 256, 256, 0, stream>>>(W2, B2t, 128, 256);
  k_w23<<<(128 * 512 + 512 + 255) / 256, 256, 0, stream>>>(W2, W3, b2, b3, W23, b23);
  k_prep3<<<(512 * 384 + 255) / 256, 256, 0, stream>>>(W3, W23, B3t);
  k_wprep<<<(512 * 384 + 255) / 256, 256, 0, stream>>>(W4, B4t, 512, 384);

  // phase A: g = segmax(h1@W2+b2)
  for (int done = 0; done < MT; done += cb) {
    int nb = (MT - done < cb) ? (MT - done) : cb;
    int pts = nb * 128;
    k_h1<<<(pts * 128) / 256, 256, 0, stream>>>(feat, perm, W1, b1, h1hi, h1lo,
                                                done * 128, pts);
    k_gemm<0, 384, 2, 256><<<swgrid(nb * 2), 256, 0, stream>>>(
        h1hi, h1lo, nullptr, nullptr, B2t, b2, segp, done, nb, g, nullptr, nullptr);
  }
  k_gsplit<<<(S * 256 + 255) / 256, 256, 0, stream>>>(g, ghi, glo, S * 256);

  // phase C: z1 = relu([g[seg]|h1]@[W3_top;W23]+b23) ; out = segmax(z1@W4+b4)
  for (int done = 0; done < MT; done += cb) {
    int nb = (MT - done < cb) ? (MT - done) : cb;
    int pts = nb * 128;
    k_h1<<<(pts * 128) / 256, 256, 0, stream>>>(feat, perm, W1, b1, h1hi, h1lo,
                                                done * 128, pts);
    k_gemm<1, 1152, 4, 0><<<swgrid(nb * 4), 256, 0, stream>>>(
        ghi, h1hi, glo, h1lo, B3t, b23, segp, done, nb, nullptr, z1hi, z1lo);
    k_gemm<2, 1536, 3, 384><<<swgrid(nb * 3), 256, 0, stream>>>(
        z1hi, z1lo, nullptr, nullptr, B4t, b4, segp, done, nb, out, nullptr, nullptr);
  }
}

// Round 9
// 2490.984 us; speedup vs baseline: 1.3564x; 1.0585x over previous
//
#include <hip/hip_runtime.h>
#include <stdint.h>

#define GAS __attribute__((address_space(1)))
#define LAS __attribute__((address_space(3)))

typedef unsigned short u16;
typedef short short8 __attribute__((ext_vector_type(8)));
typedef __bf16 bf16x8 __attribute__((ext_vector_type(8)));
typedef float floatx4 __attribute__((ext_vector_type(4)));

// ---------- bf16 helpers (RNE) ----------
__device__ __forceinline__ u16 f2bf(float f) {
  uint32_t u = __builtin_bit_cast(uint32_t, f);
  u += 0x7FFFu + ((u >> 16) & 1u);
  return (u16)(u >> 16);
}
__device__ __forceinline__ float bf2f(u16 h) {
  return __builtin_bit_cast(float, (uint32_t)h << 16);
}
__device__ __forceinline__ void split_bf(float v, u16& hi, u16& lo) {
  hi = f2bf(v);
  float r = v - bf2f(hi);
  if (!(r == r)) r = 0.f;
  lo = f2bf(r);
}

// monotone float atomic max (pos: signed max; neg: unsigned min); read-check filters losers
__device__ __forceinline__ void atomicMaxF(float* addr, float val) {
  if (!(val > *(volatile const float*)addr)) return;
  if (val >= 0.f) atomicMax((int*)addr, __builtin_bit_cast(int, val));
  else            atomicMin((unsigned int*)addr, __builtin_bit_cast(unsigned int, val));
}

__device__ __forceinline__ void async16(const void* g, const void* lds) {
  __builtin_amdgcn_global_load_lds((GAS const uint32_t*)g, (LAS uint32_t*)lds, 16, 0, 0);
}

__device__ __forceinline__ floatx4 mfma_bf16(short8 a, short8 b, floatx4 c) {
  return __builtin_amdgcn_mfma_f32_16x16x32_bf16(
      __builtin_bit_cast(bf16x8, a), __builtin_bit_cast(bf16x8, b), c, 0, 0, 0);
}

// ---------- init: g/out = -inf, hist = 0 ----------
__global__ void k_init(float* __restrict__ g, float* __restrict__ out,
                       int* __restrict__ hist, int ng, int no, int nh) {
  int i = blockIdx.x * 256 + threadIdx.x;
  if (i < ng) g[i] = -INFINITY;
  else if (i < ng + no) out[i - ng] = -INFINITY;
  else if (i < ng + no + nh) hist[i - ng - no] = 0;
}

// ---------- counting sort of points by segment ----------
__global__ void k_hist(const int* __restrict__ idx, int* __restrict__ hist, int n) {
  int p = blockIdx.x * 256 + threadIdx.x;
  if (p < n) atomicAdd(&hist[idx[p]], 1);
}

// 1 block, 1024 threads: exclusive scan of hist[4096] -> offs & cur
__global__ __launch_bounds__(1024) void k_scan(const int* __restrict__ hist,
                                               int* __restrict__ offs, int* __restrict__ cur) {
  __shared__ int buf[2][1024];
  int t = threadIdx.x;
  int local[4];
  int s = 0;
#pragma unroll
  for (int j = 0; j < 4; ++j) { local[j] = hist[t * 4 + j]; s += local[j]; }
  buf[0][t] = s;
  __syncthreads();
  int pb = 0;
  for (int d = 1; d < 1024; d <<= 1) {
    int v = buf[pb][t] + (t >= d ? buf[pb][t - d] : 0);
    buf[pb ^ 1][t] = v;
    pb ^= 1;
    __syncthreads();
  }
  int run = (t == 0) ? 0 : buf[pb][t - 1];
#pragma unroll
  for (int j = 0; j < 4; ++j) { offs[t * 4 + j] = run; cur[t * 4 + j] = run; run += local[j]; }
}

__global__ void k_scatter(const int* __restrict__ idx, int* __restrict__ cur,
                          int* __restrict__ perm, int* __restrict__ segp, int n) {
  int p = blockIdx.x * 256 + threadIdx.x;
  if (p >= n) return;
  int s = idx[p];
  int r = atomicAdd(&cur[s], 1);
  perm[r] = p;
  segp[r] = s;
}

// ---------- h1 = feat[perm]@W1 + b1 for a sorted-row chunk ----------
__global__ void k_h1(const float* __restrict__ feat, const int* __restrict__ perm,
                     const float* __restrict__ W1, const float* __restrict__ b1,
                     u16* __restrict__ h1hi, u16* __restrict__ h1lo,
                     int pt_off, int npts_chunk) {
  int gid = blockIdx.x * 256 + threadIdx.x;
  int p = gid >> 7, c = gid & 127;
  if (p >= npts_chunk) return;
  int o = perm[pt_off + p];
  float v = b1[c];
#pragma unroll
  for (int j = 0; j < 11; ++j) v += feat[o * 11 + j] * W1[j * 128 + c];
  u16 hi, lo; split_bf(v, hi, lo);
  h1hi[gid] = hi; h1lo[gid] = lo;
}

// ---------- weight preps ----------
// W[K][N] f32 -> Bt[N][3K] bf16 rows [Whi ; Wlo ; Whi]
__global__ void k_wprep(const float* __restrict__ W, u16* __restrict__ bt, int K, int N) {
  int gid = blockIdx.x * 256 + threadIdx.x;
  if (gid >= K * N) return;
  int c = gid / K, k = gid - c * K;
  float v = W[(size_t)k * N + c];
  u16 hi, lo; split_bf(v, hi, lo);
  size_t b = (size_t)c * (3 * K);
  bt[b + k] = hi; bt[b + K + k] = lo; bt[b + 2 * K + k] = hi;
}

// W23 = W2 @ W3[256:512,:]; b23 = b3 + b2 @ W3[256:512,:]
__global__ void k_w23(const float* __restrict__ W2, const float* __restrict__ W3,
                      const float* __restrict__ b2, const float* __restrict__ b3,
                      float* __restrict__ W23, float* __restrict__ b23) {
  int gid = blockIdx.x * 256 + threadIdx.x;
  if (gid < 128 * 512) {
    int j = gid >> 9, c = gid & 511;
    float s = 0.f;
#pragma unroll 4
    for (int t = 0; t < 256; ++t) s += W2[j * 256 + t] * W3[(size_t)(256 + t) * 512 + c];
    W23[gid] = s;
  } else if (gid < 128 * 512 + 512) {
    int c = gid - 128 * 512;
    float s = b3[c];
    for (int t = 0; t < 256; ++t) s += b2[t] * W3[(size_t)(256 + t) * 512 + c];
    b23[c] = s;
  }
}

// B3t[512][1152]: K=384 rows = [W3_top(256) ; W23(128)], regions [hi;lo;hi]
__global__ void k_prep3(const float* __restrict__ W3, const float* __restrict__ W23,
                        u16* __restrict__ bt) {
  int gid = blockIdx.x * 256 + threadIdx.x;
  if (gid >= 512 * 384) return;
  int c = gid / 384, k = gid - c * 384;
  float v = (k < 256) ? W3[(size_t)k * 512 + c] : W23[(size_t)(k - 256) * 512 + c];
  u16 hi, lo; split_bf(v, hi, lo);
  size_t b = (size_t)c * 1152;
  bt[b + k] = hi; bt[b + 384 + k] = lo; bt[b + 768 + k] = hi;
}

__global__ void k_gsplit(const float* __restrict__ g, u16* __restrict__ ghi,
                         u16* __restrict__ glo, int n) {
  int i = blockIdx.x * 256 + threadIdx.x;
  if (i >= n) return;
  u16 hi, lo; split_bf(g[i], hi, lo);
  ghi[i] = hi; glo[i] = lo;
}

// ---------- the workhorse GEMM (segment-sorted rows, 2-phase dbuf, T2 XOR swizzle) ----------
// C[128x128]/block, BK=64, 4 waves (2x2), 4x4 frags of 16x16x32 bf16.
// T2 swizzle (rule #21 form): global_load_lds dest stays LINEAR; the global SOURCE k-chunk is
// pre-swizzled (lane fetches chunk (lane&7)^(lane>>3)), and the ds_read address applies the
// same XOR ((kk*4+l4)^(row&7)). Bijective per 8-row stripe; spreads the old 16-way conflict
// across all 32 banks (2-way over wave64 = free).
// MODE 0: A = h1 {hi,hi,lo} stride 128, KP=384;  epi: +b2, run-reduced segmax -> g   (NT=2)
// MODE 1: A = [g[seg](256) | h1(128)] {hi,hi,lo}, KP=1152; epi: +b23, relu -> z1     (NT=4)
// MODE 2: A = z1 {hi,hi,lo} stride 512, KP=1536; epi: +b4, run-reduced segmax -> out (NT=3)
template <int MODE, int KP, int NT, int CW>
__global__ __launch_bounds__(256) void k_gemm(
    const u16* __restrict__ a0, const u16* __restrict__ a1,
    const u16* __restrict__ a2, const u16* __restrict__ a3,
    const u16* __restrict__ bt, const float* __restrict__ bias,
    const int* __restrict__ segp, int mt0, int nb,
    float* __restrict__ gmax, u16* __restrict__ whi, u16* __restrict__ wlo) {
  __shared__ __align__(16) union {
    struct { u16 A[2][128 * 64]; u16 B[2][128 * 64]; } st;
    float ct[128 * 66];
  } sm;
  const int tid = threadIdx.x;
  const int w = tid >> 6, lane = tid & 63;

  // XCD-sibling swizzle: work = mtl*NT+ct; contiguous work per XCD (assumes bid%8 = xcd)
  const int work_total = nb * NT;
  const int spx = (work_total + 7) >> 3;
  const int wk = (blockIdx.x & 7) * spx + (blockIdx.x >> 3);
  if (wk >= work_total) return;
  const int mtl = wk / NT, ct = wk - mtl * NT;

  const int wr = w & 1, wc = w >> 1;
  const int l15 = lane & 15, l4 = lane >> 4;
  const int sub = lane >> 3;
  // T2: source k-chunk pre-swizzle — lane fetches chunk (lane&7)^(row-in-stripe)
  const int kcs = (((lane & 7) ^ sub) & 7) * 8;

  int arl[4], bcol[4], gq[4];
#pragma unroll
  for (int q = 0; q < 4; ++q) {
    int rr = (q * 4 + w) * 8 + sub;
    arl[q] = mtl * 128 + rr;
    bcol[q] = ct * 128 + rr;
    if constexpr (MODE == 1) gq[q] = segp[(mt0 + mtl) * 128 + rr];
  }

  auto stage = [&](int kt, int buf) {
    const int kbase = kt * 64 + kcs;
#pragma unroll
    for (int q = 0; q < 4; ++q) {
      const u16* src;
      if constexpr (MODE == 0) {
        int r = kbase >> 7, k = kbase & 127;
        src = ((r == 2) ? a1 : a0) + (size_t)arl[q] * 128 + k;
      } else if constexpr (MODE == 1) {
        int r = kbase / 384, inner = kbase - r * 384;
        bool lo = (r == 2);
        if (inner < 256) src = (lo ? a2 : a0) + (size_t)gq[q] * 256 + inner;
        else             src = (lo ? a3 : a1) + (size_t)arl[q] * 128 + (inner - 256);
      } else {
        int r = kbase >> 9, inner = kbase & 511;
        src = ((r == 2) ? a1 : a0) + (size_t)arl[q] * 512 + inner;
      }
      async16(src, &sm.st.A[buf][(q * 4 + w) * 512]);
    }
#pragma unroll
    for (int q = 0; q < 4; ++q)
      async16(bt + (size_t)bcol[q] * KP + kbase, &sm.st.B[buf][(q * 4 + w) * 512]);
  };

  floatx4 zero = {0.f, 0.f, 0.f, 0.f};
  floatx4 acc[4][4];
#pragma unroll
  for (int mi = 0; mi < 4; ++mi)
#pragma unroll
    for (int ni = 0; ni < 4; ++ni) acc[mi][ni] = zero;

  constexpr int NKT = KP / 64;
  stage(0, 0);
  __syncthreads();
  int cur = 0;
  for (int kt = 0; kt < NKT; ++kt) {
    if (kt + 1 < NKT) stage(kt + 1, cur ^ 1);  // prefetch overlaps compute below
#pragma unroll
    for (int kk = 0; kk < 2; ++kk) {
      // T2 swizzled read: row R has R&7 == l15&7 (16-multiples drop out), so the XOR'd
      // k-chunk index is uniform across mi/ni: sa = ((kk*4+l4) ^ (l15&7)) * 8 u16.
      const int sa = (((kk * 4 + l4) ^ (l15 & 7)) & 7) * 8;
      short8 af[4], bfr[4];
#pragma unroll
      for (int mi = 0; mi < 4; ++mi)
        af[mi] = *(const short8*)&sm.st.A[cur][(wr * 64 + mi * 16 + l15) * 64 + sa];
#pragma unroll
      for (int ni = 0; ni < 4; ++ni)
        bfr[ni] = *(const short8*)&sm.st.B[cur][(wc * 64 + ni * 16 + l15) * 64 + sa];
#pragma unroll
      for (int mi = 0; mi < 4; ++mi)
#pragma unroll
        for (int ni = 0; ni < 4; ++ni)
          acc[mi][ni] = mfma_bf16(af[mi], bfr[ni], acc[mi][ni]);
    }
    __syncthreads();  // drains vmcnt (next buf staged) + proves cur fully consumed
    cur ^= 1;
  }

  if constexpr (MODE == 1) {
    // store z1 hi/lo (chunk-local, sorted order). C/D: col=lane&15, row=(lane>>4)*4+reg
#pragma unroll
    for (int ni = 0; ni < 4; ++ni) {
      const int col = ct * 128 + wc * 64 + ni * 16 + l15;
      const float bv = bias[col];
#pragma unroll
      for (int mi = 0; mi < 4; ++mi) {
        const int rl0 = mtl * 128 + wr * 64 + mi * 16 + l4 * 4;
#pragma unroll
        for (int r = 0; r < 4; ++r) {
          float v = fmaxf(acc[mi][ni][r] + bv, 0.f);
          u16 hi, lo; split_bf(v, hi, lo);
          whi[(size_t)(rl0 + r) * 512 + col] = hi;
          wlo[(size_t)(rl0 + r) * 512 + col] = lo;
        }
      }
    }
  } else {
    // run-reduced segment max: two 64-col halves through LDS [128][66] f32
#pragma unroll
    for (int h = 0; h < 2; ++h) {
      __syncthreads();
      if (wc == h) {
#pragma unroll
        for (int ni = 0; ni < 4; ++ni) {
          const int cl = ni * 16 + l15;  // 0..63 within half
          const float bv = bias[ct * 128 + h * 64 + cl];
#pragma unroll
          for (int mi = 0; mi < 4; ++mi) {
            const int row0 = wr * 64 + mi * 16 + l4 * 4;
#pragma unroll
            for (int r = 0; r < 4; ++r)
              sm.ct[(row0 + r) * 66 + cl] = acc[mi][ni][r] + bv;
          }
        }
      }
      __syncthreads();
      if (tid < 128) {
        const int col = tid & 63, rh = tid >> 6;
        const int cg = ct * 128 + h * 64 + col;
        const int base = (mt0 + mtl) * 128 + rh * 64;
        float run = sm.ct[(rh * 64) * 66 + col];
        int curs = segp[base];
        for (int r = 1; r < 64; ++r) {
          int s = segp[base + r];
          float v = sm.ct[(rh * 64 + r) * 66 + col];
          if (s != curs) {
            atomicMaxF(&gmax[(size_t)curs * CW + cg], run);
            run = v; curs = s;
          } else {
            run = fmaxf(run, v);
          }
        }
        atomicMaxF(&gmax[(size_t)curs * CW + cg], run);
      }
    }
  }
}

// ---------- launch ----------
static inline int swgrid(int work) { return 8 * ((work + 7) / 8); }

extern "C" void kernel_launch(void* const* d_in, const int* in_sizes, int n_in,
                              void* d_out, int out_size, void* d_ws, size_t ws_size,
                              hipStream_t stream) {
  const float* feat = (const float*)d_in[0];
  const int* sidx   = (const int*)d_in[1];
  const float* W1 = (const float*)d_in[3];
  const float* b1 = (const float*)d_in[4];
  const float* W2 = (const float*)d_in[5];
  const float* b2 = (const float*)d_in[6];
  const float* W3 = (const float*)d_in[7];
  const float* b3 = (const float*)d_in[8];
  const float* W4 = (const float*)d_in[9];
  const float* b4 = (const float*)d_in[10];
  float* out = (float*)d_out;
  (void)n_in;

  const int S  = out_size / 384;  // 4096
  const int NP = in_sizes[1];     // 400000 (multiple of 128)
  const int MT = NP / 128;        // 3125

  char* ws = (char*)d_ws;
  size_t off = 0;
  auto carve = [&](size_t bytes) -> void* {
    void* p = ws + off;
    off += (bytes + 255) & ~(size_t)255;
    return p;
  };
  // persistent (~15 MB)
  float* g   = (float*)carve((size_t)S * 256 * 4);
  u16* ghi   = (u16*)carve((size_t)S * 256 * 2);
  u16* glo   = (u16*)carve((size_t)S * 256 * 2);
  u16* B2t   = (u16*)carve((size_t)256 * 384 * 2);
  u16* B3t   = (u16*)carve((size_t)512 * 1152 * 2);
  u16* B4t   = (u16*)carve((size_t)384 * 1536 * 2);
  float* W23 = (float*)carve((size_t)128 * 512 * 4);
  float* b23 = (float*)carve((size_t)512 * 4);
  int* hist  = (int*)carve((size_t)S * 4);
  int* offs  = (int*)carve((size_t)S * 4);
  int* curp  = (int*)carve((size_t)S * 4);
  int* perm  = (int*)carve((size_t)NP * 4);
  int* segp  = (int*)carve((size_t)NP * 4);

  // chunk-local: per 128-row block: h1 64 KiB + z1 256 KiB
  const size_t per_block = (size_t)128 * (128 * 2 * 2 + 512 * 2 * 2) + 4 * 256;
  size_t remain = (ws_size > off + 4096) ? (ws_size - off - 4096) : 0;
  int cb = (int)(remain / per_block);
  if (cb < 1) cb = 1;
  if (cb > MT) cb = MT;
  u16* h1hi = (u16*)carve((size_t)cb * 128 * 128 * 2);
  u16* h1lo = (u16*)carve((size_t)cb * 128 * 128 * 2);
  u16* z1hi = (u16*)carve((size_t)cb * 128 * 512 * 2);
  u16* z1lo = (u16*)carve((size_t)cb * 128 * 512 * 2);

  // init + sort
  k_init<<<(S * (256 + 384 + 1) + 255) / 256, 256, 0, stream>>>(g, out, hist,
                                                                S * 256, S * 384, S);
  k_hist<<<(NP + 255) / 256, 256, 0, stream>>>(sidx, hist, NP);
  k_scan<<<1, 1024, 0, stream>>>(hist, offs, curp);
  k_scatter<<<(NP + 255) / 256, 256, 0, stream>>>(sidx, curp, perm, segp, NP);

  // weight preps
  k_wprep<<<(128 * 256 + 255) / 256, 256, 0, stream>>>(W2, B2t, 128, 256);
  k_w23<<<(128 * 512 + 512 + 255) / 256, 256, 0, stream>>>(W2, W3, b2, b3, W23, b23);
  k_prep3<<<(512 * 384 + 255) / 256, 256, 0, stream>>>(W3, W23, B3t);
  k_wprep<<<(512 * 384 + 255) / 256, 256, 0, stream>>>(W4, B4t, 512, 384);

  // phase A: g = segmax(h1@W2+b2)
  for (int done = 0; done < MT; done += cb) {
    int nb = (MT - done < cb) ? (MT - done) : cb;
    int pts = nb * 128;
    k_h1<<<(pts * 128) / 256, 256, 0, stream>>>(feat, perm, W1, b1, h1hi, h1lo,
                                                done * 128, pts);
    k_gemm<0, 384, 2, 256><<<swgrid(nb * 2), 256, 0, stream>>>(
        h1hi, h1lo, nullptr, nullptr, B2t, b2, segp, done, nb, g, nullptr, nullptr);
  }
  k_gsplit<<<(S * 256 + 255) / 256, 256, 0, stream>>>(g, ghi, glo, S * 256);

  // phase C: z1 = relu([g[seg]|h1]@[W3_top;W23]+b23) ; out = segmax(z1@W4+b4)
  for (int done = 0; done < MT; done += cb) {
    int nb = (MT - done < cb) ? (MT - done) : cb;
    int pts = nb * 128;
    k_h1<<<(pts * 128) / 256, 256, 0, stream>>>(feat, perm, W1, b1, h1hi, h1lo,
                                                done * 128, pts);
    k_gemm<1, 1152, 4, 0><<<swgrid(nb * 4), 256, 0, stream>>>(
        ghi, h1hi, glo, h1lo, B3t, b23, segp, done, nb, nullptr, z1hi, z1lo);
    k_gemm<2, 1536, 3, 384><<<swgrid(nb * 3), 256, 0, stream>>>(
        z1hi, z1lo, nullptr, nullptr, B4t, b4, segp, done, nb, out, nullptr, nullptr);
  }
}